// Round 3
// baseline (695.596 us; speedup 1.0000x reference)
//
#include <hip/hip_runtime.h>
#include <hip/hip_bf16.h>

typedef short bf16x8 __attribute__((ext_vector_type(8)));
typedef float f32x4 __attribute__((ext_vector_type(4)));
typedef unsigned short u16;

#define LOG2E 1.44269504088896340736f

__device__ __forceinline__ u16 f2bf(float f) {
    unsigned u = __float_as_uint(f);
    u += 0x7fffu + ((u >> 16) & 1u);   // round-to-nearest-even
    return (u16)(u >> 16);
}
__device__ __forceinline__ float bf2f(u16 h) {
    return __uint_as_float(((unsigned)h) << 16);
}

// ---------------------------------------------------------------------------
// Kernel 0: weight prep. Combined rows: [0,256)=Wv, [256,288)=Wq*log2e, [288,320)=Wk.
// Split each f32 weight into bf16 hi + bf16 lo. Combined bias (q-bias pre-scaled).
// ---------------------------------------------------------------------------
__global__ void k_prep(const float* __restrict__ Wq, const float* __restrict__ bq,
                       const float* __restrict__ Wk, const float* __restrict__ bk,
                       const float* __restrict__ Wv, const float* __restrict__ bv,
                       u16* __restrict__ Whi, u16* __restrict__ Wlo,
                       float* __restrict__ bias) {
    int idx = blockIdx.x * 256 + threadIdx.x;
    if (idx >= 320 * 256) return;
    int row = idx >> 8, c = idx & 255;
    float w, b;
    if (row < 256)      { w = Wv[row * 256 + c];                  b = bv[row]; }
    else if (row < 288) { w = Wq[(row - 256) * 256 + c] * LOG2E;  b = bq[row - 256] * LOG2E; }
    else                { w = Wk[(row - 288) * 256 + c];          b = bk[row - 288]; }
    u16 hi = f2bf(w);
    Whi[idx] = hi;
    Wlo[idx] = f2bf(w - bf2f(hi));
    if (c == 0) bias[row] = b;
}

// ---------------------------------------------------------------------------
// Kernel 1: fused QKV projection. out[320 rows][4096 n] per batch via MFMA.
// 3-term split product: Whi*xhi + Whi*xlo + Wlo*xhi  (~fp32 accuracy).
// Writes: vbf[b][256][4096] bf16 ; qt/kt[b][4096][64] bf16 (cols 0..31 hi, 32..63 lo)
// ---------------------------------------------------------------------------
#define XPAD 264  // xT row stride in elems (=528B, 16B-multiple, conflict-friendly)

__global__ __launch_bounds__(256) void k_proj(
    const float* __restrict__ x, const u16* __restrict__ Whi,
    const u16* __restrict__ Wlo, const float* __restrict__ bias,
    u16* __restrict__ qt, u16* __restrict__ kt, u16* __restrict__ vbf) {
    __shared__ __attribute__((aligned(16))) u16 xh[64 * XPAD];
    __shared__ __attribute__((aligned(16))) u16 xl[64 * XPAD];
    int bid = blockIdx.x;
    int b = bid & 7, nt = bid >> 3;
    int n0 = nt * 64;
    int t = threadIdx.x;
    int lane = t & 63, w = t >> 6;
    int lr = lane & 15, lk = lane >> 4;

    // ---- stage x tile transposed + bf16-split into LDS ----
    {
        int n = t & 63;
        int cg = t >> 6;
        for (int it = 0; it < 8; ++it) {
            int c8 = (it * 4 + cg) * 8;
            bf16x8 hv, lv;
#pragma unroll
            for (int u = 0; u < 8; ++u) {
                float xv = x[((size_t)(b * 256 + c8 + u)) * 4096 + n0 + n];
                u16 hu = f2bf(xv);
                hv[u] = (short)hu;
                lv[u] = (short)f2bf(xv - bf2f(hu));
            }
            *(bf16x8*)&xh[n * XPAD + c8] = hv;
            *(bf16x8*)&xl[n * XPAD + c8] = lv;
        }
    }
    __syncthreads();

    f32x4 acc[5][4];
#pragma unroll
    for (int i = 0; i < 5; i++)
#pragma unroll
        for (int j = 0; j < 4; j++) acc[i][j] = (f32x4){0.f, 0.f, 0.f, 0.f};

    for (int cs = 0; cs < 8; ++cs) {
        int c0 = cs * 32;
        bf16x8 ah[5], al[5], bh[4], bl[4];
#pragma unroll
        for (int mt = 0; mt < 5; ++mt) {
            int row = (w * 5 + mt) * 16 + lr;
            ah[mt] = *(const bf16x8*)&Whi[row * 256 + c0 + lk * 8];
            al[mt] = *(const bf16x8*)&Wlo[row * 256 + c0 + lk * 8];
        }
#pragma unroll
        for (int ns = 0; ns < 4; ++ns) {
            int np = ns * 16 + lr;
            bh[ns] = *(const bf16x8*)&xh[np * XPAD + c0 + lk * 8];
            bl[ns] = *(const bf16x8*)&xl[np * XPAD + c0 + lk * 8];
        }
#pragma unroll
        for (int mt = 0; mt < 5; ++mt)
#pragma unroll
            for (int ns = 0; ns < 4; ++ns) {
                acc[mt][ns] = __builtin_amdgcn_mfma_f32_16x16x32_bf16(ah[mt], bh[ns], acc[mt][ns], 0, 0, 0);
                acc[mt][ns] = __builtin_amdgcn_mfma_f32_16x16x32_bf16(ah[mt], bl[ns], acc[mt][ns], 0, 0, 0);
                acc[mt][ns] = __builtin_amdgcn_mfma_f32_16x16x32_bf16(al[mt], bh[ns], acc[mt][ns], 0, 0, 0);
            }
    }

    // ---- epilogue: bias + scatter to v / q(hi,lo) / k(hi,lo) ----
#pragma unroll
    for (int mt = 0; mt < 5; ++mt) {
        int tile = w * 5 + mt;  // 0..19 ; 16-row tiles never straddle v/q/k regions
#pragma unroll
        for (int ns = 0; ns < 4; ++ns) {
#pragma unroll
            for (int r = 0; r < 4; ++r) {
                int row = tile * 16 + lk * 4 + r;
                int n = n0 + ns * 16 + lr;
                float val = acc[mt][ns][r] + bias[row];
                if (row < 256) {
                    vbf[((size_t)(b * 256 + row)) * 4096 + n] = f2bf(val);
                } else if (row < 288) {
                    u16 hi = f2bf(val);
                    size_t base = ((size_t)(b * 4096 + n)) * 64 + (row - 256);
                    qt[base] = hi;
                    qt[base + 32] = f2bf(val - bf2f(hi));
                } else {
                    u16 hi = f2bf(val);
                    size_t base = ((size_t)(b * 4096 + n)) * 64 + (row - 288);
                    kt[base] = hi;
                    kt[base + 32] = f2bf(val - bf2f(hi));
                }
            }
        }
    }
}

// ---------------------------------------------------------------------------
// Kernel 2: flash attention (softmax over i), WAVE-PRIVATE design.
// Each wave owns 16 j-columns end-to-end: QK^T, online softmax (state fully
// in registers: each lane's column is lane&15), and PV over ALL 256 c-rows.
// No cross-wave state, no semantic barriers. P staged in a per-wave-private
// LDS slice (same-wave in-order DS write->read).
// OUTPUT IS FLOAT32 (reference output dtype).
// ---------------------------------------------------------------------------
#define PWS 40  // per-wave P row stride in u16 (80B: 16B-aligned, 2-way banks)

__global__ __launch_bounds__(256) void k_attn(
    const u16* __restrict__ qt, const u16* __restrict__ kt,
    const u16* __restrict__ vbf, const float* __restrict__ x,
    const float* __restrict__ gamma, float* __restrict__ out) {
    __shared__ __attribute__((aligned(16))) u16 P[4][16][PWS];
    int bid = blockIdx.x;
    int b = bid & 7, jt = bid >> 3;  // b = bid%8 pins batch -> XCD (L2 locality)
    int t = threadIdx.x;
    int lane = t & 63, w = t >> 6;
    int lr = lane & 15, lk = lane >> 4;
    int j0 = jt * 64 + w * 16;       // this wave's 16 columns

    // K fragments for this wave's 16 columns (hi and lo parts), loaded once
    size_t kb = ((size_t)(b * 4096 + j0 + lr)) * 64 + lk * 8;
    bf16x8 khi = *(const bf16x8*)&kt[kb];
    bf16x8 klo = *(const bf16x8*)&kt[kb + 32];

    f32x4 acc[16];
#pragma unroll
    for (int i = 0; i < 16; i++) acc[i] = (f32x4){0.f, 0.f, 0.f, 0.f};
    float mcur = -3.0e38f, lsum = 0.f;
    const f32x4 zero = {0.f, 0.f, 0.f, 0.f};

    for (int it = 0; it < 128; ++it) {
        int i0 = it * 32;
        // q fragments (i-rows), hi+lo — same addresses for all 4 waves -> L1 hits
        size_t qb0 = ((size_t)(b * 4096 + i0 + lr)) * 64 + lk * 8;
        size_t qb1 = ((size_t)(b * 4096 + i0 + 16 + lr)) * 64 + lk * 8;
        bf16x8 qh0 = *(const bf16x8*)&qt[qb0];
        bf16x8 ql0 = *(const bf16x8*)&qt[qb0 + 32];
        bf16x8 qh1 = *(const bf16x8*)&qt[qb1];
        bf16x8 ql1 = *(const bf16x8*)&qt[qb1 + 32];

        // S = log2e * q.k  (3-term split product, K=32 in one MFMA)
        f32x4 s0 = __builtin_amdgcn_mfma_f32_16x16x32_bf16(qh0, khi, zero, 0, 0, 0);
        s0 = __builtin_amdgcn_mfma_f32_16x16x32_bf16(qh0, klo, s0, 0, 0, 0);
        s0 = __builtin_amdgcn_mfma_f32_16x16x32_bf16(ql0, khi, s0, 0, 0, 0);
        f32x4 s1 = __builtin_amdgcn_mfma_f32_16x16x32_bf16(qh1, khi, zero, 0, 0, 0);
        s1 = __builtin_amdgcn_mfma_f32_16x16x32_bf16(qh1, klo, s1, 0, 0, 0);
        s1 = __builtin_amdgcn_mfma_f32_16x16x32_bf16(ql1, khi, s1, 0, 0, 0);

        // ---- online softmax over i; lane's column is j0 + lr ----
        float tm = fmaxf(fmaxf(fmaxf(s0[0], s0[1]), fmaxf(s0[2], s0[3])),
                         fmaxf(fmaxf(s1[0], s1[1]), fmaxf(s1[2], s1[3])));
        tm = fmaxf(tm, __shfl_xor(tm, 16));
        tm = fmaxf(tm, __shfl_xor(tm, 32));   // max over the 32 i in this tile
        float mnew = fmaxf(mcur, tm);
        float scale = exp2f(mcur - mnew);     // == 1.0f exactly when no growth
        mcur = mnew;
        lsum *= scale;
        if (__any(scale != 1.0f)) {           // pure perf skip; math identity
#pragma unroll
            for (int ct = 0; ct < 16; ++ct)
#pragma unroll
                for (int r = 0; r < 4; ++r) acc[ct][r] *= scale;
        }
        float p0 = exp2f(s0[0] - mcur), p1 = exp2f(s0[1] - mcur);
        float p2 = exp2f(s0[2] - mcur), p3 = exp2f(s0[3] - mcur);
        float p4 = exp2f(s1[0] - mcur), p5 = exp2f(s1[1] - mcur);
        float p6 = exp2f(s1[2] - mcur), p7 = exp2f(s1[3] - mcur);
        lsum += (p0 + p1) + (p2 + p3) + (p4 + p5) + (p6 + p7);

        // pack P -> bf16 into this wave's private slice: P[w][j_local][i_local]
        uint2 w0, w1;
        w0.x = ((unsigned)f2bf(p1) << 16) | f2bf(p0);
        w0.y = ((unsigned)f2bf(p3) << 16) | f2bf(p2);
        w1.x = ((unsigned)f2bf(p5) << 16) | f2bf(p4);
        w1.y = ((unsigned)f2bf(p7) << 16) | f2bf(p6);
        *(uint2*)&P[w][lr][lk * 4] = w0;         // i_local = lk*4 + 0..3  (s0 rows)
        *(uint2*)&P[w][lr][16 + lk * 4] = w1;    // i_local = 16 + lk*4 + 0..3 (s1)
        // same-wave DS pipe is in-order: reads below see the writes above
        bf16x8 bp = *(const bf16x8*)&P[w][lr][lk * 8];  // B-frag: col=lr, k=lk*8+u

        // ---- PV over ALL 256 c rows: acc[ct] += v[c-tile, i-tile] * P ----
#pragma unroll
        for (int ct = 0; ct < 16; ++ct) {
            bf16x8 av = *(const bf16x8*)&vbf[((size_t)(b * 256 + ct * 16 + lr)) * 4096 + i0 + lk * 8];
            acc[ct] = __builtin_amdgcn_mfma_f32_16x16x32_bf16(av, bp, acc[ct], 0, 0, 0);
        }
        __syncthreads();  // NON-semantic: keeps waves lockstep so the shared
                          // v/q tiles stay L1-resident across the 4 waves
    }

    // ---- epilogue: l is per-column, fully in-register; f32 output ----
    lsum += __shfl_xor(lsum, 16);
    lsum += __shfl_xor(lsum, 32);
    float linv = gamma[0] / lsum;   // this lane's column normalizer
#pragma unroll
    for (int ct = 0; ct < 16; ++ct)
#pragma unroll
        for (int r = 0; r < 4; ++r) {
            int c = ct * 16 + lk * 4 + r;
            size_t o = ((size_t)(b * 256 + c)) * 4096 + j0 + lr;
            out[o] = acc[ct][r] * linv + x[o];
        }
}

// ---------------------------------------------------------------------------
extern "C" void kernel_launch(void* const* d_in, const int* in_sizes, int n_in,
                              void* d_out, int out_size, void* d_ws, size_t ws_size,
                              hipStream_t stream) {
    const float* x = (const float*)d_in[0];
    const float* Wq = (const float*)d_in[1];
    const float* bq = (const float*)d_in[2];
    const float* Wk = (const float*)d_in[3];
    const float* bk = (const float*)d_in[4];
    const float* Wv = (const float*)d_in[5];
    const float* bv = (const float*)d_in[6];
    const float* gamma = (const float*)d_in[7];

    char* ws = (char*)d_ws;
    u16* Whi = (u16*)ws;                               // 163840 B
    u16* Wlo = (u16*)(ws + 163840);                    // 163840 B
    float* bias = (float*)(ws + 327680);               // 1280 B
    u16* qt = (u16*)(ws + 329216);                     // 4 MB  [8][4096][64]
    u16* kt = (u16*)(ws + 329216 + 4194304);           // 4 MB
    u16* vbf = (u16*)(ws + 329216 + 8388608);          // 16 MB [8][256][4096]
    // total ws use ~25.5 MB

    k_prep<<<320, 256, 0, stream>>>(Wq, bq, Wk, bk, Wv, bv, Whi, Wlo, bias);
    k_proj<<<512, 256, 0, stream>>>(x, Whi, Wlo, bias, qt, kt, vbf);
    k_attn<<<512, 256, 0, stream>>>(qt, kt, vbf, x, gamma, (float*)d_out);
}

// Round 4
// 356.277 us; speedup vs baseline: 1.9524x; 1.9524x over previous
//
#include <hip/hip_runtime.h>
#include <hip/hip_bf16.h>

typedef short bf16x8 __attribute__((ext_vector_type(8)));
typedef float f32x4 __attribute__((ext_vector_type(4)));
typedef unsigned short u16;

#define LOG2E 1.44269504088896340736f

__device__ __forceinline__ u16 f2bf(float f) {
    unsigned u = __float_as_uint(f);
    u += 0x7fffu + ((u >> 16) & 1u);   // round-to-nearest-even
    return (u16)(u >> 16);
}
__device__ __forceinline__ float bf2f(u16 h) {
    return __uint_as_float(((unsigned)h) << 16);
}

// ---------------------------------------------------------------------------
// Kernel 0: weight prep. Combined rows: [0,256)=Wv, [256,288)=Wq*log2e, [288,320)=Wk.
// Split each f32 weight into bf16 hi + bf16 lo. Combined bias (q-bias pre-scaled).
// ---------------------------------------------------------------------------
__global__ void k_prep(const float* __restrict__ Wq, const float* __restrict__ bq,
                       const float* __restrict__ Wk, const float* __restrict__ bk,
                       const float* __restrict__ Wv, const float* __restrict__ bv,
                       u16* __restrict__ Whi, u16* __restrict__ Wlo,
                       float* __restrict__ bias) {
    int idx = blockIdx.x * 256 + threadIdx.x;
    if (idx >= 320 * 256) return;
    int row = idx >> 8, c = idx & 255;
    float w, b;
    if (row < 256)      { w = Wv[row * 256 + c];                  b = bv[row]; }
    else if (row < 288) { w = Wq[(row - 256) * 256 + c] * LOG2E;  b = bq[row - 256] * LOG2E; }
    else                { w = Wk[(row - 288) * 256 + c];          b = bk[row - 288]; }
    u16 hi = f2bf(w);
    Whi[idx] = hi;
    Wlo[idx] = f2bf(w - bf2f(hi));
    if (c == 0) bias[row] = b;
}

// ---------------------------------------------------------------------------
// Kernel 1: fused QKV projection. out[320 rows][4096 n] per batch via MFMA.
// 3-term split product: Whi*xhi + Whi*xlo + Wlo*xhi  (~fp32 accuracy).
// Writes: vbf[b][256][4096] bf16 ; qt/kt[b][4096][64] bf16 (cols 0..31 hi, 32..63 lo)
// ---------------------------------------------------------------------------
#define XPAD 264  // xT row stride in elems (=528B, 16B-multiple, conflict-friendly)

__global__ __launch_bounds__(256) void k_proj(
    const float* __restrict__ x, const u16* __restrict__ Whi,
    const u16* __restrict__ Wlo, const float* __restrict__ bias,
    u16* __restrict__ qt, u16* __restrict__ kt, u16* __restrict__ vbf) {
    __shared__ __attribute__((aligned(16))) u16 xh[64 * XPAD];
    __shared__ __attribute__((aligned(16))) u16 xl[64 * XPAD];
    int bid = blockIdx.x;
    int b = bid & 7, nt = bid >> 3;
    int n0 = nt * 64;
    int t = threadIdx.x;
    int lane = t & 63, w = t >> 6;
    int lr = lane & 15, lk = lane >> 4;

    // ---- stage x tile transposed + bf16-split into LDS ----
    {
        int n = t & 63;
        int cg = t >> 6;
        for (int it = 0; it < 8; ++it) {
            int c8 = (it * 4 + cg) * 8;
            bf16x8 hv, lv;
#pragma unroll
            for (int u = 0; u < 8; ++u) {
                float xv = x[((size_t)(b * 256 + c8 + u)) * 4096 + n0 + n];
                u16 hu = f2bf(xv);
                hv[u] = (short)hu;
                lv[u] = (short)f2bf(xv - bf2f(hu));
            }
            *(bf16x8*)&xh[n * XPAD + c8] = hv;
            *(bf16x8*)&xl[n * XPAD + c8] = lv;
        }
    }
    __syncthreads();

    f32x4 acc[5][4];
#pragma unroll
    for (int i = 0; i < 5; i++)
#pragma unroll
        for (int j = 0; j < 4; j++) acc[i][j] = (f32x4){0.f, 0.f, 0.f, 0.f};

    for (int cs = 0; cs < 8; ++cs) {
        int c0 = cs * 32;
        bf16x8 ah[5], al[5], bh[4], bl[4];
#pragma unroll
        for (int mt = 0; mt < 5; ++mt) {
            int row = (w * 5 + mt) * 16 + lr;
            ah[mt] = *(const bf16x8*)&Whi[row * 256 + c0 + lk * 8];
            al[mt] = *(const bf16x8*)&Wlo[row * 256 + c0 + lk * 8];
        }
#pragma unroll
        for (int ns = 0; ns < 4; ++ns) {
            int np = ns * 16 + lr;
            bh[ns] = *(const bf16x8*)&xh[np * XPAD + c0 + lk * 8];
            bl[ns] = *(const bf16x8*)&xl[np * XPAD + c0 + lk * 8];
        }
#pragma unroll
        for (int mt = 0; mt < 5; ++mt)
#pragma unroll
            for (int ns = 0; ns < 4; ++ns) {
                acc[mt][ns] = __builtin_amdgcn_mfma_f32_16x16x32_bf16(ah[mt], bh[ns], acc[mt][ns], 0, 0, 0);
                acc[mt][ns] = __builtin_amdgcn_mfma_f32_16x16x32_bf16(ah[mt], bl[ns], acc[mt][ns], 0, 0, 0);
                acc[mt][ns] = __builtin_amdgcn_mfma_f32_16x16x32_bf16(al[mt], bh[ns], acc[mt][ns], 0, 0, 0);
            }
    }

    // ---- epilogue: bias + scatter to v / q(hi,lo) / k(hi,lo) ----
#pragma unroll
    for (int mt = 0; mt < 5; ++mt) {
        int tile = w * 5 + mt;  // 0..19 ; 16-row tiles never straddle v/q/k regions
#pragma unroll
        for (int ns = 0; ns < 4; ++ns) {
#pragma unroll
            for (int r = 0; r < 4; ++r) {
                int row = tile * 16 + lk * 4 + r;
                int n = n0 + ns * 16 + lr;
                float val = acc[mt][ns][r] + bias[row];
                if (row < 256) {
                    vbf[((size_t)(b * 256 + row)) * 4096 + n] = f2bf(val);
                } else if (row < 288) {
                    u16 hi = f2bf(val);
                    size_t base = ((size_t)(b * 4096 + n)) * 64 + (row - 256);
                    qt[base] = hi;
                    qt[base + 32] = f2bf(val - bf2f(hi));
                } else {
                    u16 hi = f2bf(val);
                    size_t base = ((size_t)(b * 4096 + n)) * 64 + (row - 288);
                    kt[base] = hi;
                    kt[base + 32] = f2bf(val - bf2f(hi));
                }
            }
        }
    }
}

// ---------------------------------------------------------------------------
// Kernel 2: flash attention (softmax over i), SHARED-P design.
// Block = 64 j-cols, 4 waves. Wave w: softmax-owner of j-subtile w (16 cols),
// PV-owner of c-chunk [w*64, w*64+64). i-tile = 64 (two K=32 MFMA rounds).
// P + rescale factors double-buffered in LDS -> ONE barrier per 64-i tile.
// All global loads issued at iteration top; __syncthreads' vmcnt drain is the
// prefetch completion point. Output f32.
// ---------------------------------------------------------------------------
#define PSTR 72  // P row stride in u16: 64 i + pad; 144B rows (16B-aligned)

__global__ __launch_bounds__(256, 2) void k_attn(
    const u16* __restrict__ qt, const u16* __restrict__ kt,
    const u16* __restrict__ vbf, const float* __restrict__ x,
    const float* __restrict__ gamma, float* __restrict__ out) {
    __shared__ __attribute__((aligned(16))) u16 P[2][4][16][PSTR];  // 18.4 KB
    __shared__ float sc[2][64];
    __shared__ float lbuf[64];
    int bid = blockIdx.x;
    int b = bid & 7, jt = bid >> 3;  // b = bid%8 pins batch -> XCD (L2 locality)
    int t = threadIdx.x;
    int lane = t & 63, w = t >> 6;
    int lr = lane & 15, lk = lane >> 4;
    int j0 = jt * 64;
    int jw = j0 + w * 16;            // this wave's softmax-owned columns

    // K fragments for this wave's 16 columns (hi and lo parts), loaded once
    size_t kb = ((size_t)(b * 4096 + jw + lr)) * 64 + lk * 8;
    bf16x8 khi = *(const bf16x8*)&kt[kb];
    bf16x8 klo = *(const bf16x8*)&kt[kb + 32];

    f32x4 acc[4][4];  // [ct][js]: c = w*64+ct*16+lk*4+r , j = j0+js*16+lr
#pragma unroll
    for (int i = 0; i < 4; i++)
#pragma unroll
        for (int j = 0; j < 4; j++) acc[i][j] = (f32x4){0.f, 0.f, 0.f, 0.f};
    float mcur = -3.0e38f, lsum = 0.f;
    const f32x4 zero = {0.f, 0.f, 0.f, 0.f};

    for (int it = 0; it < 64; ++it) {
        int i0 = it * 64;
        int p = it & 1;

        // ---- issue ALL global loads for this iteration up front ----
        bf16x8 qh[4], ql[4];
#pragma unroll
        for (int g = 0; g < 4; ++g) {
            size_t qb = ((size_t)(b * 4096 + i0 + g * 16 + lr)) * 64 + lk * 8;
            qh[g] = *(const bf16x8*)&qt[qb];
            ql[g] = *(const bf16x8*)&qt[qb + 32];
        }
        bf16x8 av[2][4];  // [ks: 32-i half][ct: c-subtile]
#pragma unroll
        for (int ks = 0; ks < 2; ++ks)
#pragma unroll
            for (int ct = 0; ct < 4; ++ct)
                av[ks][ct] = *(const bf16x8*)&vbf[((size_t)(b * 256 + w * 64 + ct * 16 + lr)) * 4096
                                                  + i0 + ks * 32 + lk * 8];

        // ---- Phase A: QK^T (3-term split) for 64 i-rows of own 16 cols ----
        f32x4 s[4];
#pragma unroll
        for (int g = 0; g < 4; ++g) {
            s[g] = __builtin_amdgcn_mfma_f32_16x16x32_bf16(qh[g], khi, zero, 0, 0, 0);
            s[g] = __builtin_amdgcn_mfma_f32_16x16x32_bf16(qh[g], klo, s[g], 0, 0, 0);
            s[g] = __builtin_amdgcn_mfma_f32_16x16x32_bf16(ql[g], khi, s[g], 0, 0, 0);
        }

        // online softmax over i (this wave's column = jw + lr)
        float tm = -3.0e38f;
#pragma unroll
        for (int g = 0; g < 4; ++g)
            tm = fmaxf(tm, fmaxf(fmaxf(s[g][0], s[g][1]), fmaxf(s[g][2], s[g][3])));
        tm = fmaxf(tm, __shfl_xor(tm, 16));
        tm = fmaxf(tm, __shfl_xor(tm, 32));
        float mnew = fmaxf(mcur, tm);
        float scale = exp2f(mcur - mnew);   // == 1.0f exactly when no growth
        mcur = mnew;
        lsum *= scale;
#pragma unroll
        for (int g = 0; g < 4; ++g) {
            float p0 = exp2f(s[g][0] - mcur), p1 = exp2f(s[g][1] - mcur);
            float p2 = exp2f(s[g][2] - mcur), p3 = exp2f(s[g][3] - mcur);
            lsum += (p0 + p1) + (p2 + p3);
            uint2 pk;
            pk.x = ((unsigned)f2bf(p1) << 16) | f2bf(p0);
            pk.y = ((unsigned)f2bf(p3) << 16) | f2bf(p2);
            // P[p][w][j_local=lr][i_local = g*16 + lk*4 + r]
            *(uint2*)&P[p][w][lr][g * 16 + lk * 4] = pk;
        }
        if (lk == 0) sc[p][w * 16 + lr] = scale;
        __syncthreads();  // publishes P/sc; implicit vmcnt drain completes av/q prefetch

        // ---- Phase B: rescale + PV for own 64-c chunk over all 64 j ----
        float rs[4];
#pragma unroll
        for (int js = 0; js < 4; ++js) rs[js] = sc[p][js * 16 + lr];
        if (__any((rs[0] != 1.f) | (rs[1] != 1.f) | (rs[2] != 1.f) | (rs[3] != 1.f))) {
#pragma unroll
            for (int ct = 0; ct < 4; ++ct)
#pragma unroll
                for (int js = 0; js < 4; ++js)
#pragma unroll
                    for (int r = 0; r < 4; ++r) acc[ct][js][r] *= rs[js];
        }
#pragma unroll
        for (int ks = 0; ks < 2; ++ks) {
            bf16x8 bp[4];
#pragma unroll
            for (int js = 0; js < 4; ++js)
                bp[js] = *(const bf16x8*)&P[p][js][lr][ks * 32 + lk * 8];
#pragma unroll
            for (int ct = 0; ct < 4; ++ct)
#pragma unroll
                for (int js = 0; js < 4; ++js)
                    acc[ct][js] = __builtin_amdgcn_mfma_f32_16x16x32_bf16(av[ks][ct], bp[js], acc[ct][js], 0, 0, 0);
        }
        // no trailing barrier: next iter writes the OTHER P buffer; the next
        // iteration's barrier separates those writes from this iter's reads.
    }

    // ---- epilogue: broadcast per-column l, then c-chunk-ordered f32 store ----
    lsum += __shfl_xor(lsum, 16);
    lsum += __shfl_xor(lsum, 32);
    __syncthreads();               // protect lbuf (fresh) ordering across waves
    if (lk == 0) lbuf[w * 16 + lr] = lsum;
    __syncthreads();
    float g = gamma[0];
    float linv[4];
#pragma unroll
    for (int js = 0; js < 4; ++js) linv[js] = g / lbuf[js * 16 + lr];
#pragma unroll
    for (int ct = 0; ct < 4; ++ct)
#pragma unroll
        for (int r = 0; r < 4; ++r) {
            int c = w * 64 + ct * 16 + lk * 4 + r;
            size_t base = ((size_t)(b * 256 + c)) * 4096 + j0;
#pragma unroll
            for (int js = 0; js < 4; ++js) {
                int j = js * 16 + lr;
                out[base + j] = acc[ct][js][r] * linv[js] + x[base + j];
            }
        }
}

// ---------------------------------------------------------------------------
extern "C" void kernel_launch(void* const* d_in, const int* in_sizes, int n_in,
                              void* d_out, int out_size, void* d_ws, size_t ws_size,
                              hipStream_t stream) {
    const float* x = (const float*)d_in[0];
    const float* Wq = (const float*)d_in[1];
    const float* bq = (const float*)d_in[2];
    const float* Wk = (const float*)d_in[3];
    const float* bk = (const float*)d_in[4];
    const float* Wv = (const float*)d_in[5];
    const float* bv = (const float*)d_in[6];
    const float* gamma = (const float*)d_in[7];

    char* ws = (char*)d_ws;
    u16* Whi = (u16*)ws;                               // 163840 B
    u16* Wlo = (u16*)(ws + 163840);                    // 163840 B
    float* bias = (float*)(ws + 327680);               // 1280 B
    u16* qt = (u16*)(ws + 329216);                     // 4 MB  [8][4096][64]
    u16* kt = (u16*)(ws + 329216 + 4194304);           // 4 MB
    u16* vbf = (u16*)(ws + 329216 + 8388608);          // 16 MB [8][256][4096]
    // total ws use ~25.5 MB

    k_prep<<<320, 256, 0, stream>>>(Wq, bq, Wk, bk, Wv, bv, Whi, Wlo, bias);
    k_proj<<<512, 256, 0, stream>>>(x, Whi, Wlo, bias, qt, kt, vbf);
    k_attn<<<512, 256, 0, stream>>>(qt, kt, vbf, x, gamma, (float*)d_out);
}